// Round 3
// baseline (307.742 us; speedup 1.0000x reference)
//
#include <hip/hip_runtime.h>
#include <math.h>

constexpr int N_ = 64, C_ = 64, T_ = 256, V_ = 25;
constexpr int L_ = 3, S_ = 3, IC_ = 16, K_ = 5;
constexpr int TT = 8, TB = T_ / TT;          // 32 t-blocks
constexpr int SITES = TT * V_;               // 200
constexpr int CHTV = T_ * V_;                // 6400 floats per channel plane
constexpr int XP = 20;                       // row pad: 80 B, 16B-aligned, 8 bank-quads

// 1/sqrt(1+1e-5)
#define RS 0.99999500003750f

// ---------------------------------------------------------------------------
// k_transpose_A: AT[i][j][u][v] = A[i][j][v][u]  (makes k_main's A reads
// coalesced: lane-varying v is the fastest axis). 22.5 KB, L1-resident.
// ---------------------------------------------------------------------------
__global__ __launch_bounds__(256)
void k_transpose_A(const float* __restrict__ A, float* __restrict__ AT) {
    int e = blockIdx.x * 256 + threadIdx.x;
    if (e < L_ * S_ * V_ * V_) {
        int ij = e / (V_ * V_), r = e % (V_ * V_), u = r / V_, v = r % V_;
        AT[e] = A[(size_t)ij * V_ * V_ + v * V_ + u];
    }
}

// ---------------------------------------------------------------------------
// k_main: ONE x pass computes down-conv for all 3 layers (dacc[48]), xd for
// all layers goes to fp32 LDS, ONE barrier, then edge-partials + 3x graph
// conv + mix + fused final BN/residual/ReLU (channels 0..47).
// Weights/BN via wave-uniform scalar loads; A via coalesced global (L1-hot).
// ---------------------------------------------------------------------------
__global__ __launch_bounds__(256, 3)
void k_main(const float* __restrict__ x,
            const float* __restrict__ AT,
            const float* __restrict__ w_down,
            const float* __restrict__ b_down,
            const float* __restrict__ g_down,
            const float* __restrict__ bt_down,
            const float* __restrict__ w_sub,
            const float* __restrict__ b_sub,
            const float* __restrict__ g_sub,
            const float* __restrict__ bt_sub,
            const float* __restrict__ g_bn,
            const float* __restrict__ b_bn,
            float* __restrict__ out,
            float* __restrict__ partial) {
    __shared__ float s_xd[L_][TT][V_][XP];   // 48 KB -> 3 blocks/CU

    const int tid = threadIdx.x;
    const int n = blockIdx.x / TB, tb = blockIdx.x % TB;
    const int t0 = tb * TT;
    const bool act = tid < SITES;
    const int tt = tid / V_, v = tid % V_;
    const size_t base = (size_t)n * C_ * CHTV + (size_t)(t0 + tt) * V_ + v;

    // ---- phase 1: down conv for ALL 3 layers in one x pass ----
    if (act) {
        float dacc[L_ * IC_];
#pragma unroll
        for (int l = 0; l < L_ * IC_; ++l) dacc[l] = 0.f;
        for (int ch2 = 0; ch2 < 2; ++ch2) {
            float xv[32];
#pragma unroll
            for (int q = 0; q < 32; ++q)
                xv[q] = x[base + (size_t)(ch2 * 32 + q) * CHTV];
#pragma unroll
            for (int l = 0; l < L_ * IC_; ++l) {
                const float* wr = &w_down[l * C_ + ch2 * 32];
                float s = dacc[l];
#pragma unroll
                for (int q = 0; q < 32; ++q) s = fmaf(wr[q], xv[q], s);
                dacc[l] = s;
            }
        }
        float r[L_ * IC_];
#pragma unroll
        for (int l = 0; l < L_ * IC_; ++l) {
            float sd = g_down[l] * RS;
            float bd = fmaf(b_down[l], sd, bt_down[l]);
            r[l] = fmaxf(fmaf(dacc[l], sd, bd), 0.f);
        }
#pragma unroll
        for (int i = 0; i < L_; ++i) {
            float4* row = (float4*)&s_xd[i][tt][v][0];
#pragma unroll
            for (int w = 0; w < 4; ++w)
                row[w] = make_float4(r[i * IC_ + w * 4 + 0], r[i * IC_ + w * 4 + 1],
                                     r[i * IC_ + w * 4 + 2], r[i * IC_ + w * 4 + 3]);
        }
    }
    __syncthreads();   // the ONLY barrier

    // ---- edge-branch partial sums over this t-tile (fp32, all layers) ----
#pragma unroll
    for (int i = 0; i < L_; ++i) {
        for (int e = tid; e < IC_ * V_; e += 256) {
            int c = e / V_, vv = e % V_;
            float s = 0.f;
#pragma unroll
            for (int q = 0; q < TT; ++q) s += s_xd[i][q][vv][c];
            partial[(((size_t)i * N_ + n) * TB + tb) * (IC_ * V_) + e] = s;
        }
    }

    // ---- phase 2 + epilogue (active sites only) ----
    if (act) {
        float acc[S_][IC_];
#pragma unroll
        for (int j = 0; j < S_; ++j)
#pragma unroll
            for (int o = 0; o < IC_; ++o) acc[j][o] = 0.f;

        for (int i = 0; i < L_; ++i) {
            float p[S_][IC_];
#pragma unroll
            for (int j = 0; j < S_; ++j)
#pragma unroll
                for (int c = 0; c < IC_; ++c) p[j][c] = 0.f;

            const float* At = AT + (size_t)i * S_ * V_ * V_;
#pragma unroll 5
            for (int u = 0; u < V_; ++u) {
                const float4* xr = (const float4*)&s_xd[i][tt][u][0];
                float4 x0 = xr[0], x1 = xr[1], x2 = xr[2], x3 = xr[3];
                float a0 = At[u * V_ + v];
                float a1 = At[V_ * V_ + u * V_ + v];
                float a2 = At[2 * V_ * V_ + u * V_ + v];
#define FMA16(J, AJ)                                                     \
                p[J][0]  = fmaf(AJ, x0.x, p[J][0]);                      \
                p[J][1]  = fmaf(AJ, x0.y, p[J][1]);                      \
                p[J][2]  = fmaf(AJ, x0.z, p[J][2]);                      \
                p[J][3]  = fmaf(AJ, x0.w, p[J][3]);                      \
                p[J][4]  = fmaf(AJ, x1.x, p[J][4]);                      \
                p[J][5]  = fmaf(AJ, x1.y, p[J][5]);                      \
                p[J][6]  = fmaf(AJ, x1.z, p[J][6]);                      \
                p[J][7]  = fmaf(AJ, x1.w, p[J][7]);                      \
                p[J][8]  = fmaf(AJ, x2.x, p[J][8]);                      \
                p[J][9]  = fmaf(AJ, x2.y, p[J][9]);                      \
                p[J][10] = fmaf(AJ, x2.z, p[J][10]);                     \
                p[J][11] = fmaf(AJ, x2.w, p[J][11]);                     \
                p[J][12] = fmaf(AJ, x3.x, p[J][12]);                     \
                p[J][13] = fmaf(AJ, x3.y, p[J][13]);                     \
                p[J][14] = fmaf(AJ, x3.z, p[J][14]);                     \
                p[J][15] = fmaf(AJ, x3.w, p[J][15]);
                FMA16(0, a0)
                FMA16(1, a1)
                FMA16(2, a2)
#undef FMA16
            }
            // channel mix + folded sub-BN (uniform scalar weight loads)
#pragma unroll
            for (int j = 0; j < S_; ++j) {
#pragma unroll
                for (int o = 0; o < IC_; ++o) {
                    const int gi = (i * S_ + j) * IC_ + o;
                    const float* wr = &w_sub[(size_t)gi * IC_];
                    float h = 0.f;
#pragma unroll
                    for (int c = 0; c < IC_; ++c) h = fmaf(wr[c], p[j][c], h);
                    float ss = g_sub[gi] * RS;
                    float sk = fmaf(b_sub[gi], ss, bt_sub[gi]);
                    acc[j][o] += fmaf(h, ss, sk);
                }
            }
        }

        // epilogue: final BN + residual + ReLU, channels 0..47
#pragma unroll
        for (int j = 0; j < S_; ++j)
#pragma unroll
            for (int o = 0; o < IC_; ++o) {
                const int chn = j * IC_ + o;
                float sb = g_bn[chn] * RS;
                float val = fmaf(acc[j][o], sb, b_bn[chn]) + x[base + (size_t)chn * CHTV];
                out[base + (size_t)chn * CHTV] = fmaxf(val, 0.f);
            }
    }
}

// ---------------------------------------------------------------------------
// k_edge: per-n top-k + edge conv, summed over layers -> esum[N][IC][V]
// ---------------------------------------------------------------------------
__global__ __launch_bounds__(256, 2)
void k_edge(const float* __restrict__ partial,
            const float* __restrict__ w_edge,
            const float* __restrict__ g_edge,
            const float* __restrict__ bt_edge,
            float* __restrict__ esum) {
    __shared__ float s_xt[V_][IC_];
    __shared__ float s_in[V_][V_];
    __shared__ int   s_id[V_][K_];
    __shared__ float s_we[IC_][2 * IC_];
    __shared__ float s_se[IC_], s_be[IC_];
    const int tid = threadIdx.x;
    const int n = blockIdx.x;
    float eacc[2] = {0.f, 0.f};

    for (int i = 0; i < L_; ++i) {
        __syncthreads();
        for (int e = tid; e < IC_ * 2 * IC_; e += 256)
            ((float*)s_we)[e] = w_edge[i * IC_ * 2 * IC_ + e];
        if (tid < IC_) {
            s_se[tid] = g_edge[i * IC_ + tid] * RS;
            s_be[tid] = bt_edge[i * IC_ + tid];
        }
        for (int e = tid; e < IC_ * V_; e += 256) {
            int c = e / V_, v = e % V_;
            float s = 0.f;
            for (int tb = 0; tb < TB; ++tb)
                s += partial[(((size_t)i * N_ + n) * TB + tb) * (IC_ * V_) + e];
            s_xt[v][c] = s * (1.f / T_);
        }
        __syncthreads();
        for (int e = tid; e < V_ * V_; e += 256) {
            int v = e / V_, u = e % V_;
            float s = 0.f;
#pragma unroll
            for (int c = 0; c < IC_; ++c) s += s_xt[v][c] * s_xt[u][c];
            s_in[v][u] = s;
        }
        __syncthreads();
        if (tid < V_) {
            int v = tid;
            float xxv = s_in[v][v];
            unsigned mask = 0;
            for (int k = 0; k < K_; ++k) {
                float best = -1e30f; int bi = 0;
                for (int u = 0; u < V_; ++u) {
                    if (mask & (1u << u)) continue;
                    float pd = 2.f * s_in[v][u] - xxv - s_in[u][u];
                    if (pd > best) { best = pd; bi = u; }   // tie -> lowest u
                }
                mask |= 1u << bi;
                s_id[v][k] = bi;
            }
        }
        __syncthreads();
#pragma unroll 2
        for (int rep = 0; rep < 2; ++rep) {
            int e = tid + rep * 256;
            if (e < IC_ * V_) {
                int o = e / V_, v = e % V_;
                float bse = 0.f;
#pragma unroll
                for (int c = 0; c < IC_; ++c)
                    bse += s_xt[v][c] * (s_we[o][IC_ + c] - s_we[o][c]);
                float m = -1e30f;
#pragma unroll
                for (int k = 0; k < K_; ++k) {
                    int u = s_id[v][k];
                    float s = bse;
#pragma unroll
                    for (int c = 0; c < IC_; ++c) s += s_xt[u][c] * s_we[o][c];
                    float hb = fmaf(s, s_se[o], s_be[o]);
                    hb = hb >= 0.f ? hb : 0.2f * hb;
                    m = fmaxf(m, hb);
                }
                eacc[rep] += m;
            }
        }
    }
#pragma unroll 2
    for (int rep = 0; rep < 2; ++rep) {
        int e = tid + rep * 256;
        if (e < IC_ * V_) esum[(size_t)n * IC_ * V_ + e] = eacc[rep];
    }
}

// ---------------------------------------------------------------------------
// k_edge_out: out channels 48..63 = relu(bn(esum) + x), broadcast over T
// ---------------------------------------------------------------------------
__global__ __launch_bounds__(256)
void k_edge_out(const float* __restrict__ x,
                const float* __restrict__ esum,
                const float* __restrict__ g_bn,
                const float* __restrict__ b_bn,
                float* __restrict__ out) {
    const int gid = blockIdx.x * 256 + threadIdx.x;     // [0, 64*16*1600)
    const int n = gid / (IC_ * 1600);
    const int r = gid % (IC_ * 1600);
    const int o = r / 1600;
    const int q = r % 1600;
    const int chn = 48 + o;
    const size_t fo = ((size_t)n * C_ + chn) * 1600 + q;   // float4 index
    float4 xv = ((const float4*)x)[fo];
    float sb = g_bn[chn] * RS;
    float bb = b_bn[chn];
    const float* es = &esum[(size_t)n * IC_ * V_ + o * V_];
    float4 ov;
    {
        int p = q * 4;
        float r0 = fmaf(es[(p + 0) % V_], sb, bb) + xv.x;
        float r1 = fmaf(es[(p + 1) % V_], sb, bb) + xv.y;
        float r2 = fmaf(es[(p + 2) % V_], sb, bb) + xv.z;
        float r3 = fmaf(es[(p + 3) % V_], sb, bb) + xv.w;
        ov.x = fmaxf(r0, 0.f); ov.y = fmaxf(r1, 0.f);
        ov.z = fmaxf(r2, 0.f); ov.w = fmaxf(r3, 0.f);
    }
    ((float4*)out)[fo] = ov;
}

// ---------------------------------------------------------------------------
extern "C" void kernel_launch(void* const* d_in, const int* in_sizes, int n_in,
                              void* d_out, int out_size, void* d_ws, size_t ws_size,
                              hipStream_t stream) {
    (void)in_sizes; (void)n_in; (void)out_size; (void)ws_size;
    const float* x       = (const float*)d_in[0];
    const float* A       = (const float*)d_in[1];
    const float* w_down  = (const float*)d_in[2];
    const float* b_down  = (const float*)d_in[3];
    const float* g_down  = (const float*)d_in[4];
    const float* bt_down = (const float*)d_in[5];
    const float* w_sub   = (const float*)d_in[6];
    const float* b_sub   = (const float*)d_in[7];
    const float* g_sub   = (const float*)d_in[8];
    const float* bt_sub  = (const float*)d_in[9];
    const float* w_edge  = (const float*)d_in[10];
    const float* g_edge  = (const float*)d_in[11];
    const float* bt_edge = (const float*)d_in[12];
    const float* g_bn    = (const float*)d_in[13];
    const float* b_bn    = (const float*)d_in[14];
    float* out = (float*)d_out;

    float* AT      = (float*)d_ws;                                   // [3][3][25][25]
    float* partial = AT + (size_t)L_ * S_ * V_ * V_;                 // [3][64][32][400]
    float* esum    = partial + (size_t)L_ * N_ * TB * IC_ * V_;      // [64][400]

    hipLaunchKernelGGL(k_transpose_A, dim3((L_ * S_ * V_ * V_ + 255) / 256), dim3(256),
                       0, stream, A, AT);
    hipLaunchKernelGGL(k_main, dim3(N_ * TB), dim3(256), 0, stream,
                       x, AT, w_down, b_down, g_down, bt_down,
                       w_sub, b_sub, g_sub, bt_sub, g_bn, b_bn, out, partial);
    hipLaunchKernelGGL(k_edge, dim3(N_), dim3(256), 0, stream,
                       partial, w_edge, g_edge, bt_edge, esum);
    hipLaunchKernelGGL(k_edge_out, dim3(N_ * IC_ * 1600 / 256), dim3(256), 0, stream,
                       x, esum, g_bn, b_bn, out);
}

// Round 4
// 244.217 us; speedup vs baseline: 1.2601x; 1.2601x over previous
//
#include <hip/hip_runtime.h>
#include <math.h>

constexpr int N_ = 64, C_ = 64, T_ = 256, V_ = 25;
constexpr int L_ = 3, S_ = 3, IC_ = 16, K_ = 5;
constexpr int TT = 8, TB = T_ / TT;          // 32 t-blocks
constexpr int CHTV = T_ * V_;                // 6400 floats per channel plane

// 1/sqrt(1+1e-5)
#define RS 0.99999500003750f

// ---------------------------------------------------------------------------
// k_transpose_A: AT[i][j][u][v] = A[i][j][v][u]  (lane-varying v fastest ->
// coalesced/broadcast reads in k_main). 22.5 KB, L1/L2-resident.
// ---------------------------------------------------------------------------
__global__ __launch_bounds__(256)
void k_transpose_A(const float* __restrict__ A, float* __restrict__ AT) {
    int e = blockIdx.x * 256 + threadIdx.x;
    if (e < L_ * S_ * V_ * V_) {
        int ij = e / (V_ * V_), r = e % (V_ * V_), u = r / V_, v = r % V_;
        AT[e] = A[(size_t)ij * V_ * V_ + v * V_ + u];
    }
}

// ---------------------------------------------------------------------------
// k_main: single x pass -> down-conv all 3 layers -> xd in LDS (38.4 KB,
// 4 blocks/CU) -> one barrier -> edge partials + graph convs + mix + fused
// final BN/residual/ReLU (channels 0..47).
// Thread mapping: wave = tid/64 covers tt = {2*wave, 2*wave+1}; lane&31 = v
// (v<25 active). A wave's phase-2 LDS broadcast rows come from 2 tt-groups
// 25 rows (odd parity) apart -> conflict-free at unpadded 64B rows.
// ---------------------------------------------------------------------------
__global__ __launch_bounds__(256, 4)
void k_main(const float* __restrict__ x,
            const float* __restrict__ AT,
            const float* __restrict__ w_down,
            const float* __restrict__ b_down,
            const float* __restrict__ g_down,
            const float* __restrict__ bt_down,
            const float* __restrict__ w_sub,
            const float* __restrict__ b_sub,
            const float* __restrict__ g_sub,
            const float* __restrict__ bt_sub,
            const float* __restrict__ g_bn,
            const float* __restrict__ b_bn,
            float* __restrict__ out,
            float* __restrict__ partial) {
    __shared__ float s_xd[L_][TT][V_][IC_];   // 38.4 KB -> 4 blocks/CU

    const int tid = threadIdx.x;
    const int n = blockIdx.x / TB, tb = blockIdx.x % TB;
    const int t0 = tb * TT;
    const int tt = (tid >> 6) * 2 + ((tid >> 5) & 1);   // 2 tt-groups per wave
    const int v = tid & 31;
    const bool act = v < V_;
    const size_t base = (size_t)n * C_ * CHTV + (size_t)(t0 + tt) * V_ + v;

    // ---- phase 1: down conv for ALL 3 layers in one x pass ----
    if (act) {
        float dacc[L_ * IC_];
#pragma unroll
        for (int l = 0; l < L_ * IC_; ++l) dacc[l] = 0.f;
        for (int ch2 = 0; ch2 < 2; ++ch2) {
            float xv[32];
#pragma unroll
            for (int q = 0; q < 32; ++q)
                xv[q] = x[base + (size_t)(ch2 * 32 + q) * CHTV];
#pragma unroll
            for (int l = 0; l < L_ * IC_; ++l) {
                const float* wr = &w_down[l * C_ + ch2 * 32];
                float s = dacc[l];
#pragma unroll
                for (int q = 0; q < 32; ++q) s = fmaf(wr[q], xv[q], s);
                dacc[l] = s;
            }
        }
#pragma unroll
        for (int i = 0; i < L_; ++i) {
            float4* row = (float4*)&s_xd[i][tt][v][0];
#pragma unroll
            for (int w = 0; w < 4; ++w) {
                float r0, r1, r2, r3;
                {
                    int l0 = i * IC_ + w * 4;
                    float sd0 = g_down[l0 + 0] * RS, sd1 = g_down[l0 + 1] * RS;
                    float sd2 = g_down[l0 + 2] * RS, sd3 = g_down[l0 + 3] * RS;
                    r0 = fmaxf(fmaf(dacc[l0 + 0], sd0, fmaf(b_down[l0 + 0], sd0, bt_down[l0 + 0])), 0.f);
                    r1 = fmaxf(fmaf(dacc[l0 + 1], sd1, fmaf(b_down[l0 + 1], sd1, bt_down[l0 + 1])), 0.f);
                    r2 = fmaxf(fmaf(dacc[l0 + 2], sd2, fmaf(b_down[l0 + 2], sd2, bt_down[l0 + 2])), 0.f);
                    r3 = fmaxf(fmaf(dacc[l0 + 3], sd3, fmaf(b_down[l0 + 3], sd3, bt_down[l0 + 3])), 0.f);
                }
                row[w] = make_float4(r0, r1, r2, r3);
            }
        }
    }
    __syncthreads();   // the ONLY barrier

    // ---- edge-branch partial sums (vv-major layout: e = vv*16 + c) ----
#pragma unroll
    for (int i = 0; i < L_; ++i) {
        for (int e = tid; e < IC_ * V_; e += 256) {
            int c = e & 15, vv = e >> 4;
            float s = 0.f;
#pragma unroll
            for (int q = 0; q < TT; ++q) s += s_xd[i][q][vv][c];
            partial[(((size_t)i * N_ + n) * TB + tb) * (IC_ * V_) + e] = s;
        }
    }

    // ---- phase 2 + epilogue (active sites only) ----
    if (act) {
        float acc[S_][IC_];
#pragma unroll
        for (int j = 0; j < S_; ++j)
#pragma unroll
            for (int o = 0; o < IC_; ++o) acc[j][o] = 0.f;

        for (int i = 0; i < L_; ++i) {
            float p[S_][IC_];
#pragma unroll
            for (int j = 0; j < S_; ++j)
#pragma unroll
                for (int c = 0; c < IC_; ++c) p[j][c] = 0.f;

            const float* At = AT + (size_t)i * S_ * V_ * V_;
#pragma unroll 5
            for (int u = 0; u < V_; ++u) {
                const float4* xr = (const float4*)&s_xd[i][tt][u][0];
                float4 x0 = xr[0], x1 = xr[1], x2 = xr[2], x3 = xr[3];
                float a0 = At[u * V_ + v];
                float a1 = At[V_ * V_ + u * V_ + v];
                float a2 = At[2 * V_ * V_ + u * V_ + v];
#define FMA16(J, AJ)                                                     \
                p[J][0]  = fmaf(AJ, x0.x, p[J][0]);                      \
                p[J][1]  = fmaf(AJ, x0.y, p[J][1]);                      \
                p[J][2]  = fmaf(AJ, x0.z, p[J][2]);                      \
                p[J][3]  = fmaf(AJ, x0.w, p[J][3]);                      \
                p[J][4]  = fmaf(AJ, x1.x, p[J][4]);                      \
                p[J][5]  = fmaf(AJ, x1.y, p[J][5]);                      \
                p[J][6]  = fmaf(AJ, x1.z, p[J][6]);                      \
                p[J][7]  = fmaf(AJ, x1.w, p[J][7]);                      \
                p[J][8]  = fmaf(AJ, x2.x, p[J][8]);                      \
                p[J][9]  = fmaf(AJ, x2.y, p[J][9]);                      \
                p[J][10] = fmaf(AJ, x2.z, p[J][10]);                     \
                p[J][11] = fmaf(AJ, x2.w, p[J][11]);                     \
                p[J][12] = fmaf(AJ, x3.x, p[J][12]);                     \
                p[J][13] = fmaf(AJ, x3.y, p[J][13]);                     \
                p[J][14] = fmaf(AJ, x3.z, p[J][14]);                     \
                p[J][15] = fmaf(AJ, x3.w, p[J][15]);
                FMA16(0, a0)
                FMA16(1, a1)
                FMA16(2, a2)
#undef FMA16
            }
            // channel mix + folded sub-BN (uniform scalar weight loads)
#pragma unroll
            for (int j = 0; j < S_; ++j) {
#pragma unroll
                for (int o = 0; o < IC_; ++o) {
                    const int gi = (i * S_ + j) * IC_ + o;
                    const float* wr = &w_sub[(size_t)gi * IC_];
                    float h = 0.f;
#pragma unroll
                    for (int c = 0; c < IC_; ++c) h = fmaf(wr[c], p[j][c], h);
                    float ss = g_sub[gi] * RS;
                    float sk = fmaf(b_sub[gi], ss, bt_sub[gi]);
                    acc[j][o] += fmaf(h, ss, sk);
                }
            }
        }

        // epilogue: final BN + residual + ReLU, channels 0..47
#pragma unroll
        for (int j = 0; j < S_; ++j)
#pragma unroll
            for (int o = 0; o < IC_; ++o) {
                const int chn = j * IC_ + o;
                float sb = g_bn[chn] * RS;
                float val = fmaf(acc[j][o], sb, b_bn[chn]) + x[base + (size_t)chn * CHTV];
                out[base + (size_t)chn * CHTV] = fmaxf(val, 0.f);
            }
    }
}

// ---------------------------------------------------------------------------
// k_edge: per-n top-k + edge conv, summed over layers -> esum[N][IC][V]
// partial layout is vv-major: e = vv*16 + c
// ---------------------------------------------------------------------------
__global__ __launch_bounds__(256, 2)
void k_edge(const float* __restrict__ partial,
            const float* __restrict__ w_edge,
            const float* __restrict__ g_edge,
            const float* __restrict__ bt_edge,
            float* __restrict__ esum) {
    __shared__ float s_xt[V_][IC_];
    __shared__ float s_in[V_][V_];
    __shared__ int   s_id[V_][K_];
    __shared__ float s_we[IC_][2 * IC_];
    __shared__ float s_se[IC_], s_be[IC_];
    const int tid = threadIdx.x;
    const int n = blockIdx.x;
    float eacc[2] = {0.f, 0.f};

    for (int i = 0; i < L_; ++i) {
        __syncthreads();
        for (int e = tid; e < IC_ * 2 * IC_; e += 256)
            ((float*)s_we)[e] = w_edge[i * IC_ * 2 * IC_ + e];
        if (tid < IC_) {
            s_se[tid] = g_edge[i * IC_ + tid] * RS;
            s_be[tid] = bt_edge[i * IC_ + tid];
        }
        for (int e = tid; e < IC_ * V_; e += 256) {
            int c = e & 15, v = e >> 4;
            float s = 0.f;
            for (int tb = 0; tb < TB; ++tb)
                s += partial[(((size_t)i * N_ + n) * TB + tb) * (IC_ * V_) + e];
            s_xt[v][c] = s * (1.f / T_);
        }
        __syncthreads();
        for (int e = tid; e < V_ * V_; e += 256) {
            int v = e / V_, u = e % V_;
            float s = 0.f;
#pragma unroll
            for (int c = 0; c < IC_; ++c) s += s_xt[v][c] * s_xt[u][c];
            s_in[v][u] = s;
        }
        __syncthreads();
        if (tid < V_) {
            int v = tid;
            float xxv = s_in[v][v];
            unsigned mask = 0;
            for (int k = 0; k < K_; ++k) {
                float best = -1e30f; int bi = 0;
                for (int u = 0; u < V_; ++u) {
                    if (mask & (1u << u)) continue;
                    float pd = 2.f * s_in[v][u] - xxv - s_in[u][u];
                    if (pd > best) { best = pd; bi = u; }   // tie -> lowest u
                }
                mask |= 1u << bi;
                s_id[v][k] = bi;
            }
        }
        __syncthreads();
#pragma unroll 2
        for (int rep = 0; rep < 2; ++rep) {
            int e = tid + rep * 256;
            if (e < IC_ * V_) {
                int o = e / V_, v = e % V_;
                float bse = 0.f;
#pragma unroll
                for (int c = 0; c < IC_; ++c)
                    bse += s_xt[v][c] * (s_we[o][IC_ + c] - s_we[o][c]);
                float m = -1e30f;
#pragma unroll
                for (int k = 0; k < K_; ++k) {
                    int u = s_id[v][k];
                    float s = bse;
#pragma unroll
                    for (int c = 0; c < IC_; ++c) s += s_xt[u][c] * s_we[o][c];
                    float hb = fmaf(s, s_se[o], s_be[o]);
                    hb = hb >= 0.f ? hb : 0.2f * hb;
                    m = fmaxf(m, hb);
                }
                eacc[rep] += m;
            }
        }
    }
#pragma unroll 2
    for (int rep = 0; rep < 2; ++rep) {
        int e = tid + rep * 256;
        if (e < IC_ * V_) esum[(size_t)n * IC_ * V_ + e] = eacc[rep];
    }
}

// ---------------------------------------------------------------------------
// k_edge_out: out channels 48..63 = relu(bn(esum) + x), broadcast over T
// ---------------------------------------------------------------------------
__global__ __launch_bounds__(256)
void k_edge_out(const float* __restrict__ x,
                const float* __restrict__ esum,
                const float* __restrict__ g_bn,
                const float* __restrict__ b_bn,
                float* __restrict__ out) {
    const int gid = blockIdx.x * 256 + threadIdx.x;     // [0, 64*16*1600)
    const int n = gid / (IC_ * 1600);
    const int r = gid % (IC_ * 1600);
    const int o = r / 1600;
    const int q = r % 1600;
    const int chn = 48 + o;
    const size_t fo = ((size_t)n * C_ + chn) * 1600 + q;   // float4 index
    float4 xv = ((const float4*)x)[fo];
    float sb = g_bn[chn] * RS;
    float bb = b_bn[chn];
    const float* es = &esum[(size_t)n * IC_ * V_ + o * V_];
    float4 ov;
    {
        int p = q * 4;
        float r0 = fmaf(es[(p + 0) % V_], sb, bb) + xv.x;
        float r1 = fmaf(es[(p + 1) % V_], sb, bb) + xv.y;
        float r2 = fmaf(es[(p + 2) % V_], sb, bb) + xv.z;
        float r3 = fmaf(es[(p + 3) % V_], sb, bb) + xv.w;
        ov.x = fmaxf(r0, 0.f); ov.y = fmaxf(r1, 0.f);
        ov.z = fmaxf(r2, 0.f); ov.w = fmaxf(r3, 0.f);
    }
    ((float4*)out)[fo] = ov;
}

// ---------------------------------------------------------------------------
extern "C" void kernel_launch(void* const* d_in, const int* in_sizes, int n_in,
                              void* d_out, int out_size, void* d_ws, size_t ws_size,
                              hipStream_t stream) {
    (void)in_sizes; (void)n_in; (void)out_size; (void)ws_size;
    const float* x       = (const float*)d_in[0];
    const float* A       = (const float*)d_in[1];
    const float* w_down  = (const float*)d_in[2];
    const float* b_down  = (const float*)d_in[3];
    const float* g_down  = (const float*)d_in[4];
    const float* bt_down = (const float*)d_in[5];
    const float* w_sub   = (const float*)d_in[6];
    const float* b_sub   = (const float*)d_in[7];
    const float* g_sub   = (const float*)d_in[8];
    const float* bt_sub  = (const float*)d_in[9];
    const float* w_edge  = (const float*)d_in[10];
    const float* g_edge  = (const float*)d_in[11];
    const float* bt_edge = (const float*)d_in[12];
    const float* g_bn    = (const float*)d_in[13];
    const float* b_bn    = (const float*)d_in[14];
    float* out = (float*)d_out;

    float* AT      = (float*)d_ws;                                   // [3][3][25][25]
    float* partial = AT + (size_t)L_ * S_ * V_ * V_;                 // [3][64][32][400]
    float* esum    = partial + (size_t)L_ * N_ * TB * IC_ * V_;      // [64][400]

    hipLaunchKernelGGL(k_transpose_A, dim3((L_ * S_ * V_ * V_ + 255) / 256), dim3(256),
                       0, stream, A, AT);
    hipLaunchKernelGGL(k_main, dim3(N_ * TB), dim3(256), 0, stream,
                       x, AT, w_down, b_down, g_down, bt_down,
                       w_sub, b_sub, g_sub, bt_sub, g_bn, b_bn, out, partial);
    hipLaunchKernelGGL(k_edge, dim3(N_), dim3(256), 0, stream,
                       partial, w_edge, g_edge, bt_edge, esum);
    hipLaunchKernelGGL(k_edge_out, dim3(N_ * IC_ * 1600 / 256), dim3(256), 0, stream,
                       x, esum, g_bn, b_bn, out);
}

// Round 5
// 151.515 us; speedup vs baseline: 2.0311x; 1.6118x over previous
//
#include <hip/hip_runtime.h>
#include <hip/hip_bf16.h>
#include <math.h>

constexpr int N_ = 64, C_ = 64, T_ = 256, V_ = 25;
constexpr int L_ = 3, S_ = 3, IC_ = 16, K_ = 5;
constexpr int TT = 8, TB = T_ / TT;          // 32 t-blocks
constexpr int CHTV = T_ * V_;                // 6400 floats per channel plane

// 1/sqrt(1+1e-5)
#define RS 0.99999500003750f

using bf16x8 = __attribute__((ext_vector_type(8))) short;
using f32x16 = __attribute__((ext_vector_type(16))) float;

union FRG { uint4 q; bf16x8 b; unsigned int u[4]; };

__device__ __forceinline__ unsigned short bfr(float f) {
    __hip_bfloat16 h = __float2bfloat16(f);
    return *reinterpret_cast<unsigned short*>(&h);
}
__device__ __forceinline__ float bff(unsigned short u) {
    __hip_bfloat16 h;
    *reinterpret_cast<unsigned short*>(&h) = u;
    return __bfloat162float(h);
}
__device__ __forceinline__ unsigned int bfpk(float a, float b) {
    return (unsigned int)bfr(a) | ((unsigned int)bfr(b) << 16);
}

// ---------------------------------------------------------------------------
// k_prep: build MFMA lane-layout fragment tables (32x32x16 bf16).
// A-op layout assumed: row = lane&31, k = (lane>>5)*8 + jj (jj=0..7)
// B-op layout assumed: col = lane&31, k = (lane>>5)*8 + jj
// C/D layout (verified): col = lane&31, row = (reg&3)+8*(reg>>2)+4*(lane>>5)
// AdjF : [ij][ks2][64][4dw]   A[v][u], zero-padded v,u>=25
// WdF  : [nt2][ks4][hl2][64][4dw]  w_down[col][ch], hi/lo split, col>=48 -> 0
// WsubF: [ij][64][4dw]        w_sub[o][c] * ss(i,j,o), o>=16 -> 0
// SK   : [j][o] = sum_i (b_sub*ss + bt_sub)
// ---------------------------------------------------------------------------
__global__ void k_prep(const float* __restrict__ A,
                       const float* __restrict__ w_down,
                       const float* __restrict__ w_sub,
                       const float* __restrict__ g_sub,
                       const float* __restrict__ b_sub,
                       const float* __restrict__ bt_sub,
                       unsigned int* __restrict__ AdjF,
                       unsigned int* __restrict__ WdF,
                       unsigned int* __restrict__ WsubF,
                       float* __restrict__ SK) {
    const int tid = threadIdx.x;
    for (int e = tid; e < L_ * S_ * 2 * 64; e += 256) {
        int l = e & 63, ks = (e >> 6) & 1, ij = e >> 7;
        int v = l & 31, h = l >> 5;
        for (int dd = 0; dd < 4; ++dd) {
            float f[2];
            for (int s = 0; s < 2; ++s) {
                int u = ks * 16 + h * 8 + dd * 2 + s;
                f[s] = (v < V_ && u < V_) ? A[(ij * V_ + v) * V_ + u] : 0.f;
            }
            AdjF[e * 4 + dd] = bfpk(f[0], f[1]);
        }
    }
    for (int e = tid; e < 2 * 4 * 2 * 64; e += 256) {
        int l = e & 63, hl = (e >> 6) & 1, ks = (e >> 7) & 3, nt = e >> 9;
        int col = nt * 32 + (l & 31), h = l >> 5;
        for (int dd = 0; dd < 4; ++dd) {
            float f[2];
            for (int s = 0; s < 2; ++s) {
                int ch = ks * 16 + h * 8 + dd * 2 + s;
                float w0 = (col < 48) ? w_down[col * C_ + ch] : 0.f;
                float whi = bff(bfr(w0));
                f[s] = hl ? (w0 - whi) : w0;
            }
            WdF[e * 4 + dd] = bfpk(f[0], f[1]);
        }
    }
    for (int e = tid; e < L_ * S_ * 64; e += 256) {
        int l = e & 63, ij = e >> 6;
        int o = l & 31, h = l >> 5;
        for (int dd = 0; dd < 4; ++dd) {
            float f[2];
            for (int s = 0; s < 2; ++s) {
                int c = h * 8 + dd * 2 + s;
                float w0 = 0.f;
                if (o < IC_) {
                    float ss = g_sub[ij * IC_ + o] * RS;
                    w0 = w_sub[(ij * IC_ + o) * IC_ + c] * ss;
                }
                f[s] = w0;
            }
            WsubF[e * 4 + dd] = bfpk(f[0], f[1]);
        }
    }
    if (tid < S_ * IC_) {
        int j = tid / IC_, o = tid % IC_;
        float s = 0.f;
        for (int i = 0; i < L_; ++i) {
            int gi = (i * S_ + j) * IC_ + o;
            float ss = g_sub[gi] * RS;
            s += fmaf(b_sub[gi], ss, bt_sub[gi]);
        }
        SK[tid] = s;
    }
}

// ---------------------------------------------------------------------------
// k_main: MFMA pipeline per (n, t-tile of 8):
//  phase 1: D1[site32, col48] = X * Wd^T  (split-bf16, fp32-grade)
//  BN+ReLU in regs -> xd bf16 to LDS; fp32 edge partials via sequential-wave
//  LDS reduction (deterministic, no atomics)
//  phase 2: per (t,i,j): M2 = xd * (ss*Wsub)^T ; Y_j += Adj * M2
//           (graph B-frag assembled in-register via v_permlane32_swap_b32)
//  epilogue: final BN + residual + ReLU, channels 0..47
// ---------------------------------------------------------------------------
__global__ __launch_bounds__(256, 4)
void k_main(const float* __restrict__ x,
            const unsigned int* __restrict__ AdjF,
            const unsigned int* __restrict__ WdF,
            const unsigned int* __restrict__ WsubF,
            const float* __restrict__ SK,
            const float* __restrict__ g_down,
            const float* __restrict__ b_down,
            const float* __restrict__ bt_down,
            const float* __restrict__ g_bn,
            const float* __restrict__ b_bn,
            float* __restrict__ out,
            float* __restrict__ partial) {
    __shared__ unsigned short s_xd[L_][TT][32][16];   // 24 KB bf16 xd
    __shared__ float s_pl[48 * 32];                   // 6 KB fp32 partials

    const int tid = threadIdx.x;
    const int w = tid >> 6, l = tid & 63;
    const int v = l & 31, h = l >> 5;
    const int n = blockIdx.x / TB, tb = blockIdx.x % TB;
    const int t0 = tb * TT;
    const int vc = v < 24 ? v : 24;    // clamp pad lanes (finite garbage rows)

    for (int e = tid; e < 48 * 32; e += 256) s_pl[e] = 0.f;
    __syncthreads();

    // ---- phase 1: down-conv GEMM, split-bf16 ----
    f32x16 acc[2][2];
#pragma unroll
    for (int mt = 0; mt < 2; ++mt)
#pragma unroll
        for (int nt = 0; nt < 2; ++nt)
#pragma unroll
            for (int q = 0; q < 16; ++q) acc[mt][nt][q] = 0.f;

#pragma unroll
    for (int mt = 0; mt < 2; ++mt) {
        const int t = 2 * w + mt;
        const size_t xb = (size_t)n * C_ * CHTV + (size_t)(t0 + t) * V_ + vc;
        float xv[32];
#pragma unroll
        for (int q = 0; q < 32; ++q) {
            int ch = (q >> 3) * 16 + h * 8 + (q & 7);
            xv[q] = x[xb + (size_t)ch * CHTV];
        }
#pragma unroll
        for (int ks = 0; ks < 4; ++ks) {
            FRG ah, al;
#pragma unroll
            for (int dd = 0; dd < 4; ++dd) {
                float f0 = xv[ks * 8 + dd * 2], f1 = xv[ks * 8 + dd * 2 + 1];
                unsigned short h0 = bfr(f0), h1 = bfr(f1);
                ah.u[dd] = (unsigned int)h0 | ((unsigned int)h1 << 16);
                al.u[dd] = bfpk(f0 - bff(h0), f1 - bff(h1));
            }
#pragma unroll
            for (int nt = 0; nt < 2; ++nt) {
                FRG bh, bl;
                bh.q = *(const uint4*)&WdF[((nt * 8 + ks * 2 + 0) * 64 + l) * 4];
                bl.q = *(const uint4*)&WdF[((nt * 8 + ks * 2 + 1) * 64 + l) * 4];
                acc[mt][nt] = __builtin_amdgcn_mfma_f32_32x32x16_bf16(ah.b, bh.b, acc[mt][nt], 0, 0, 0);
                acc[mt][nt] = __builtin_amdgcn_mfma_f32_32x32x16_bf16(ah.b, bl.b, acc[mt][nt], 0, 0, 0);
                acc[mt][nt] = __builtin_amdgcn_mfma_f32_32x32x16_bf16(al.b, bh.b, acc[mt][nt], 0, 0, 0);
            }
        }
    }

    // ---- BN + ReLU; xd -> LDS (bf16); stash fp32 per-wave partial sums ----
    float psum[2][16];
#pragma unroll
    for (int nt = 0; nt < 2; ++nt) {
        const int col = nt * 32 + (l & 31);
        const bool valid = col < 48;
        float sd = 0.f, bd = 0.f;
        if (valid) {
            sd = g_down[col] * RS;
            bd = fmaf(b_down[col], sd, bt_down[col]);
        }
        const int i_ = col >> 4, c_ = col & 15;
#pragma unroll
        for (int r = 0; r < 16; ++r) {
            float x0 = fmaxf(fmaf(acc[0][nt][r], sd, bd), 0.f);
            float x1 = fmaxf(fmaf(acc[1][nt][r], sd, bd), 0.f);
            psum[nt][r] = x0 + x1;
            if (valid) {
                int vr = (r & 3) + 8 * (r >> 2) + 4 * h;
                s_xd[i_][2 * w + 0][vr][c_] = bfr(x0);
                s_xd[i_][2 * w + 1][vr][c_] = bfr(x1);
            }
        }
    }
    // deterministic cross-wave fp32 accumulation (fixed wave order)
    for (int ws_ = 0; ws_ < 4; ++ws_) {
        if (w == ws_) {
#pragma unroll
            for (int nt = 0; nt < 2; ++nt) {
                const int col = nt * 32 + (l & 31);
                if (col < 48) {
#pragma unroll
                    for (int r = 0; r < 16; ++r) {
                        int vr = (r & 3) + 8 * (r >> 2) + 4 * h;
                        int idx = col * 32 + (vr ^ (col & 31));
                        if (ws_ == 0) s_pl[idx] = psum[nt][r];
                        else          s_pl[idx] += psum[nt][r];
                    }
                }
            }
        }
        __syncthreads();
    }

    // ---- edge partials to global (layout [i][n][tb][vv*16+c], fp32) ----
    for (int e = tid; e < L_ * V_ * IC_; e += 256) {
        int i_ = e / 400, r = e - i_ * 400;
        int vv = r >> 4, c_ = r & 15;
        int col = i_ * 16 + c_;
        partial[(((size_t)i_ * N_ + n) * TB + tb) * (IC_ * V_) + r] =
            s_pl[col * 32 + (vv ^ (col & 31))];
    }

    // ---- phase 2 + epilogue ----
#pragma unroll
    for (int mt = 0; mt < 2; ++mt) {
        const int t = 2 * w + mt;
        f32x16 Y[3];
#pragma unroll
        for (int j = 0; j < 3; ++j)
#pragma unroll
            for (int q = 0; q < 16; ++q) Y[j][q] = 0.f;

#pragma unroll
        for (int i_ = 0; i_ < L_; ++i_) {
            FRG xf;
            xf.q = *(const uint4*)&s_xd[i_][t][v][h * 8];
#pragma unroll
            for (int j = 0; j < S_; ++j) {
                FRG wf;
                wf.q = *(const uint4*)&WsubF[((i_ * 3 + j) * 64 + l) * 4];
                f32x16 m2;
#pragma unroll
                for (int q = 0; q < 16; ++q) m2[q] = 0.f;
                m2 = __builtin_amdgcn_mfma_f32_32x32x16_bf16(xf.b, wf.b, m2, 0, 0, 0);
                unsigned int P0[4], P1[4];
#pragma unroll
                for (int q = 0; q < 4; ++q) {
                    P0[q] = bfpk(m2[4 * q + 0], m2[4 * q + 1]);
                    P1[q] = bfpk(m2[4 * q + 2], m2[4 * q + 3]);
                }
#pragma unroll
                for (int ks = 0; ks < 2; ++ks) {
                    unsigned int a0 = P0[2 * ks], b0 = P0[2 * ks + 1];
                    unsigned int a1 = P1[2 * ks], b1 = P1[2 * ks + 1];
                    asm volatile("v_permlane32_swap_b32 %0, %1" : "+v"(a0), "+v"(b0));
                    asm volatile("v_permlane32_swap_b32 %0, %1" : "+v"(a1), "+v"(b1));
                    FRG bfv, af;
                    bfv.u[0] = a0; bfv.u[1] = a1; bfv.u[2] = b0; bfv.u[3] = b1;
                    af.q = *(const uint4*)&AdjF[(((i_ * 3 + j) * 2 + ks) * 64 + l) * 4];
                    Y[j] = __builtin_amdgcn_mfma_f32_32x32x16_bf16(af.b, bfv.b, Y[j], 0, 0, 0);
                }
            }
        }
        // epilogue: final BN + residual + ReLU for this t, channels 0..47
        const int o = l & 31;
        if (o < IC_) {
#pragma unroll
            for (int j = 0; j < S_; ++j) {
                const int chn = j * IC_ + o;
                const float sb = g_bn[chn] * RS, bb = b_bn[chn];
                const float sk = SK[j * IC_ + o];
                const size_t ob = ((size_t)n * C_ + chn) * CHTV + (size_t)(t0 + t) * V_;
#pragma unroll
                for (int q = 0; q < 4; ++q) {
                    const int vb = 8 * q + 4 * h;
#pragma unroll
                    for (int s = 0; s < 4; ++s) {
                        const int vv = vb + s;
                        if (vv < V_) {
                            float val = fmaf(Y[j][4 * q + s] + sk, sb, bb) + x[ob + vv];
                            out[ob + vv] = fmaxf(val, 0.f);
                        }
                    }
                }
            }
        }
    }
}

// ---------------------------------------------------------------------------
// k_edge: per-n top-k + edge conv, summed over layers -> esum[N][IC][V]
// partial layout is vv-major: e = vv*16 + c
// ---------------------------------------------------------------------------
__global__ __launch_bounds__(256, 2)
void k_edge(const float* __restrict__ partial,
            const float* __restrict__ w_edge,
            const float* __restrict__ g_edge,
            const float* __restrict__ bt_edge,
            float* __restrict__ esum) {
    __shared__ float s_xt[V_][IC_];
    __shared__ float s_in[V_][V_];
    __shared__ int   s_id[V_][K_];
    __shared__ float s_we[IC_][2 * IC_];
    __shared__ float s_se[IC_], s_be[IC_];
    const int tid = threadIdx.x;
    const int n = blockIdx.x;
    float eacc[2] = {0.f, 0.f};

    for (int i = 0; i < L_; ++i) {
        __syncthreads();
        for (int e = tid; e < IC_ * 2 * IC_; e += 256)
            ((float*)s_we)[e] = w_edge[i * IC_ * 2 * IC_ + e];
        if (tid < IC_) {
            s_se[tid] = g_edge[i * IC_ + tid] * RS;
            s_be[tid] = bt_edge[i * IC_ + tid];
        }
        for (int e = tid; e < IC_ * V_; e += 256) {
            int c = e & 15, v = e >> 4;
            float s = 0.f;
            for (int tb = 0; tb < TB; ++tb)
                s += partial[(((size_t)i * N_ + n) * TB + tb) * (IC_ * V_) + e];
            s_xt[v][c] = s * (1.f / T_);
        }
        __syncthreads();
        for (int e = tid; e < V_ * V_; e += 256) {
            int v = e / V_, u = e % V_;
            float s = 0.f;
#pragma unroll
            for (int c = 0; c < IC_; ++c) s += s_xt[v][c] * s_xt[u][c];
            s_in[v][u] = s;
        }
        __syncthreads();
        if (tid < V_) {
            int v = tid;
            float xxv = s_in[v][v];
            unsigned mask = 0;
            for (int k = 0; k < K_; ++k) {
                float best = -1e30f; int bi = 0;
                for (int u = 0; u < V_; ++u) {
                    if (mask & (1u << u)) continue;
                    float pd = 2.f * s_in[v][u] - xxv - s_in[u][u];
                    if (pd > best) { best = pd; bi = u; }   // tie -> lowest u
                }
                mask |= 1u << bi;
                s_id[v][k] = bi;
            }
        }
        __syncthreads();
#pragma unroll 2
        for (int rep = 0; rep < 2; ++rep) {
            int e = tid + rep * 256;
            if (e < IC_ * V_) {
                int o = e / V_, v = e % V_;
                float bse = 0.f;
#pragma unroll
                for (int c = 0; c < IC_; ++c)
                    bse += s_xt[v][c] * (s_we[o][IC_ + c] - s_we[o][c]);
                float m = -1e30f;
#pragma unroll
                for (int k = 0; k < K_; ++k) {
                    int u = s_id[v][k];
                    float s = bse;
#pragma unroll
                    for (int c = 0; c < IC_; ++c) s += s_xt[u][c] * s_we[o][c];
                    float hb = fmaf(s, s_se[o], s_be[o]);
                    hb = hb >= 0.f ? hb : 0.2f * hb;
                    m = fmaxf(m, hb);
                }
                eacc[rep] += m;
            }
        }
    }
#pragma unroll 2
    for (int rep = 0; rep < 2; ++rep) {
        int e = tid + rep * 256;
        if (e < IC_ * V_) esum[(size_t)n * IC_ * V_ + e] = eacc[rep];
    }
}

// ---------------------------------------------------------------------------
// k_edge_out: out channels 48..63 = relu(bn(esum) + x), broadcast over T
// ---------------------------------------------------------------------------
__global__ __launch_bounds__(256)
void k_edge_out(const float* __restrict__ x,
                const float* __restrict__ esum,
                const float* __restrict__ g_bn,
                const float* __restrict__ b_bn,
                float* __restrict__ out) {
    const int gid = blockIdx.x * 256 + threadIdx.x;     // [0, 64*16*1600)
    const int n = gid / (IC_ * 1600);
    const int r = gid % (IC_ * 1600);
    const int o = r / 1600;
    const int q = r % 1600;
    const int chn = 48 + o;
    const size_t fo = ((size_t)n * C_ + chn) * 1600 + q;   // float4 index
    float4 xv = ((const float4*)x)[fo];
    float sb = g_bn[chn] * RS;
    float bb = b_bn[chn];
    const float* es = &esum[(size_t)n * IC_ * V_ + o * V_];
    float4 ov;
    {
        int p = q * 4;
        float r0 = fmaf(es[(p + 0) % V_], sb, bb) + xv.x;
        float r1 = fmaf(es[(p + 1) % V_], sb, bb) + xv.y;
        float r2 = fmaf(es[(p + 2) % V_], sb, bb) + xv.z;
        float r3 = fmaf(es[(p + 3) % V_], sb, bb) + xv.w;
        ov.x = fmaxf(r0, 0.f); ov.y = fmaxf(r1, 0.f);
        ov.z = fmaxf(r2, 0.f); ov.w = fmaxf(r3, 0.f);
    }
    ((float4*)out)[fo] = ov;
}

// ---------------------------------------------------------------------------
extern "C" void kernel_launch(void* const* d_in, const int* in_sizes, int n_in,
                              void* d_out, int out_size, void* d_ws, size_t ws_size,
                              hipStream_t stream) {
    (void)in_sizes; (void)n_in; (void)out_size; (void)ws_size;
    const float* x       = (const float*)d_in[0];
    const float* A       = (const float*)d_in[1];
    const float* w_down  = (const float*)d_in[2];
    const float* b_down  = (const float*)d_in[3];
    const float* g_down  = (const float*)d_in[4];
    const float* bt_down = (const float*)d_in[5];
    const float* w_sub   = (const float*)d_in[6];
    const float* b_sub   = (const float*)d_in[7];
    const float* g_sub   = (const float*)d_in[8];
    const float* bt_sub  = (const float*)d_in[9];
    const float* w_edge  = (const float*)d_in[10];
    const float* g_edge  = (const float*)d_in[11];
    const float* bt_edge = (const float*)d_in[12];
    const float* g_bn    = (const float*)d_in[13];
    const float* b_bn    = (const float*)d_in[14];
    float* out = (float*)d_out;

    unsigned int* AdjF  = (unsigned int*)d_ws;                 // 4608 dw
    unsigned int* WdF   = AdjF + L_ * S_ * 2 * 64 * 4;         // 4096 dw
    unsigned int* WsubF = WdF + 2 * 4 * 2 * 64 * 4;            // 2304 dw
    float* SK           = (float*)(WsubF + L_ * S_ * 64 * 4);  // 48 (+pad)
    float* partial      = SK + 64;                             // [3][64][32][400]
    float* esum         = partial + (size_t)L_ * N_ * TB * IC_ * V_;  // [64][400]

    hipLaunchKernelGGL(k_prep, dim3(1), dim3(256), 0, stream,
                       A, w_down, w_sub, g_sub, b_sub, bt_sub,
                       AdjF, WdF, WsubF, SK);
    hipLaunchKernelGGL(k_main, dim3(N_ * TB), dim3(256), 0, stream,
                       x, AdjF, WdF, WsubF, SK,
                       g_down, b_down, bt_down, g_bn, b_bn, out, partial);
    hipLaunchKernelGGL(k_edge, dim3(N_), dim3(256), 0, stream,
                       partial, w_edge, g_edge, bt_edge, esum);
    hipLaunchKernelGGL(k_edge_out, dim3(N_ * IC_ * 1600 / 256), dim3(256), 0, stream,
                       x, esum, g_bn, b_bn, out);
}